// Round 5
// baseline (435.032 us; speedup 1.0000x reference)
//
#include <hip/hip_runtime.h>

#define SDIM 2048
#define DDIM 1024
#define NH 16
#define DK 64
#define NB 2
#define MROWS (NB * SDIM) // 4096
#define MAXEV 65536
#define EXPC 0.18033688011112f // 0.125 * log2(e)

typedef _Float16 f16x8 __attribute__((ext_vector_type(8)));
typedef _Float16 f16x4 __attribute__((ext_vector_type(4)));
typedef float f32x4 __attribute__((ext_vector_type(4)));

__device__ __forceinline__ void ld_lds16(const _Float16* g, _Float16* l) {
  __builtin_amdgcn_global_load_lds(
      (const __attribute__((address_space(1))) void*)g,
      (__attribute__((address_space(3))) void*)l, 16, 0, 0);
}

// ---------- K0: fp32 -> fp16 convert, all four arrays in one launch ----------
__global__ __launch_bounds__(256) void cvt_f16(
    const float* __restrict__ x, const float* __restrict__ wq,
    const float* __restrict__ wk, const float* __restrict__ wv,
    _Float16* __restrict__ xh, _Float16* __restrict__ wqh,
    _Float16* __restrict__ wkh, _Float16* __restrict__ wvh) {
  int i = blockIdx.x * 256 + threadIdx.x; // float4 index
  const float* src;
  _Float16* dst;
  int off;
  if (i < 1048576) {
    src = x; dst = xh; off = i;
  } else if (i < 1310720) {
    src = wq; dst = wqh; off = i - 1048576;
  } else if (i < 1572864) {
    src = wk; dst = wkh; off = i - 1310720;
  } else {
    src = wv; dst = wvh; off = i - 1572864;
  }
  float4 v = ((const float4*)src)[off];
  f16x4 h;
  h[0] = (_Float16)v.x; h[1] = (_Float16)v.y;
  h[2] = (_Float16)v.z; h[3] = (_Float16)v.w;
  ((f16x4*)dst)[off] = h;
}

// ---------- K1: fused QKV projection, plain fp16 MFMA, 128x128 tile, BK=64 ----------
__global__ __launch_bounds__(256, 2) void proj_gemm(
    const _Float16* __restrict__ xh, const _Float16* __restrict__ Wqh,
    const _Float16* __restrict__ Wkh, const _Float16* __restrict__ Wvh,
    const float* __restrict__ bq, const float* __restrict__ bk,
    const float* __restrict__ bv, _Float16* __restrict__ Qo,
    _Float16* __restrict__ Ko, float* __restrict__ Vo) {
  __shared__ _Float16 sA[128 * 64]; // 16KB, XOR-swizzled chunks
  __shared__ _Float16 sB[128 * 64];
  const int t = threadIdx.x;
  const int lane = t & 63, wv = t >> 6;
  const int lr = lane & 15, quad = lane >> 4;
  const int wm = wv >> 1, wn = wv & 1;
  const int m0 = blockIdx.y * 128, n0 = blockIdx.x * 128;
  const int z = blockIdx.z;
  const _Float16* Bp = z == 0 ? Wqh : (z == 1 ? Wkh : Wvh);
  const float* bias = z == 0 ? bq : (z == 1 ? bk : bv);

  const int strow = t >> 3;            // 0..31 per issue
  const int stchunk = t & 7;           // phys chunk
  const int stsrc = (stchunk ^ (strow & 7)) * 8; // src col (halfs)

  f32x4 acc[4][4];
#pragma unroll
  for (int i = 0; i < 4; ++i)
#pragma unroll
    for (int j = 0; j < 4; ++j) acc[i][j] = (f32x4){0.f, 0.f, 0.f, 0.f};

  for (int k0 = 0; k0 < DDIM; k0 += 64) {
    __syncthreads(); // prior LDS reads complete
#pragma unroll
    for (int i = 0; i < 4; ++i) {
      const int row = i * 32 + strow;
      ld_lds16(&xh[(size_t)(m0 + row) * DDIM + k0 + stsrc],
               &sA[row * 64 + stchunk * 8]);
      ld_lds16(&Bp[(size_t)(n0 + row) * DDIM + k0 + stsrc],
               &sB[row * 64 + stchunk * 8]);
    }
    __syncthreads(); // drains vmcnt: LDS visible
    f16x8 af[4][2], bf[4][2];
#pragma unroll
    for (int i = 0; i < 4; ++i)
#pragma unroll
      for (int kk = 0; kk < 2; ++kk) {
        const int ph = ((kk * 4 + quad) ^ (lr & 7)) * 8;
        af[i][kk] = *(const f16x8*)&sA[(wm * 64 + i * 16 + lr) * 64 + ph];
        bf[i][kk] = *(const f16x8*)&sB[(wn * 64 + i * 16 + lr) * 64 + ph];
      }
#pragma unroll
    for (int kk = 0; kk < 2; ++kk)
#pragma unroll
      for (int i = 0; i < 4; ++i)
#pragma unroll
        for (int j = 0; j < 4; ++j)
          acc[i][j] = __builtin_amdgcn_mfma_f32_16x16x32_f16(
              af[i][kk], bf[j][kk], acc[i][j], 0, 0, 0);
  }
  // epilogue: bias + head-split store (C layout: col=lane&15, row=quad*4+r)
#pragma unroll
  for (int j = 0; j < 4; ++j) {
    const int ng = n0 + wn * 64 + j * 16 + lr;
    const float bvv = bias[ng];
    const int h = ng >> 6, d = ng & 63;
#pragma unroll
    for (int i = 0; i < 4; ++i) {
#pragma unroll
      for (int r = 0; r < 4; ++r) {
        const int mg = m0 + wm * 64 + i * 16 + quad * 4 + r;
        const int b = mg >> 11, s = mg & 2047;
        const float o = acc[i][j][r] + bvv;
        const size_t off = ((size_t)(b * NH + h) * SDIM + s) * DK + d;
        if (z == 0)
          Qo[off] = (_Float16)o;
        else if (z == 1)
          Ko[off] = (_Float16)o;
        else
          Vo[off] = o;
      }
    }
  }
}

// ---------- K2: row denominators. LDS-free, barrier-free; bh on fast grid dim
// so all blocks sharing a K-head land on one XCD (bh % 8). ----------
__global__ __launch_bounds__(256) void attn_denom(const _Float16* __restrict__ Q,
                                                  const _Float16* __restrict__ K,
                                                  float* __restrict__ invDen) {
  const int t = threadIdx.x;
  const int lane = t & 63, wave = t >> 6;
  const int quad = lane >> 4, lr = lane & 15;
  const int bh = blockIdx.x;          // fast dim -> XCD = bh % 8
  const int q0 = blockIdx.y * 64;
  const _Float16* Qh = Q + (size_t)bh * SDIM * DK;
  const _Float16* Kh = K + (size_t)bh * SDIM * DK;
  const size_t qoff = (size_t)(q0 + wave * 16 + lr) * DK + quad * 8;
  const f16x8 aq0 = *(const f16x8*)&Qh[qoff];
  const f16x8 aq1 = *(const f16x8*)&Qh[qoff + 32];
  float dsum[4] = {0.f, 0.f, 0.f, 0.f};
#pragma unroll 4
  for (int k = 0; k < SDIM; k += 16) {
    const f16x8 b0 = *(const f16x8*)&Kh[(size_t)(k + lr) * DK + quad * 8];
    const f16x8 b1 = *(const f16x8*)&Kh[(size_t)(k + lr) * DK + 32 + quad * 8];
    f32x4 acc = {0.f, 0.f, 0.f, 0.f};
    acc = __builtin_amdgcn_mfma_f32_16x16x32_f16(aq0, b0, acc, 0, 0, 0);
    acc = __builtin_amdgcn_mfma_f32_16x16x32_f16(aq1, b1, acc, 0, 0, 0);
#pragma unroll
    for (int r = 0; r < 4; ++r)
      dsum[r] += __builtin_amdgcn_exp2f(acc[r] * EXPC);
  }
#pragma unroll
  for (int m = 1; m < 16; m <<= 1)
#pragma unroll
    for (int r = 0; r < 4; ++r)
      dsum[r] += __shfl_xor(dsum[r], m, 64);
  if (lr == 0) {
#pragma unroll
    for (int r = 0; r < 4; ++r)
      invDen[(size_t)bh * SDIM + q0 + wave * 16 + quad * 4 + r] =
          1.0f / dsum[r];
  }
}

// ---------- K3: probs -> att_sum/att_mask. LDS-free hot loop (B-frags are
// wave-invariant -> direct global reads, L1 broadcast); one __any branch per
// head for the (never-occurring) p>=0.1 events; LDS only for epilogue. ----------
__global__ __launch_bounds__(256) void attn_pass2(
    const _Float16* __restrict__ Q, const _Float16* __restrict__ K,
    const float* __restrict__ invDen, float* __restrict__ attSum,
    float* __restrict__ attMask, float4* __restrict__ ev,
    int* __restrict__ ecnt) {
  __shared__ float Tbuf[64 * 68]; // epilogue transpose only
  const int t = threadIdx.x;
  const int lane = t & 63, wave = t >> 6;
  const int quad = lane >> 4, lr = lane & 15;
  const int k0 = blockIdx.x * 64; // fast dim -> XCD = k0tile % 8
  const int q0 = blockIdx.y * 64;
  const int b = blockIdx.z;

  const size_t qbase = ((size_t)(b * NH) * SDIM + q0 + wave * 16 + lr) * DK;
  const size_t dbase = (size_t)(b * NH) * SDIM + q0 + wave * 16 + quad * 4;
  const size_t hstep = (size_t)SDIM * DK;

  float asum[4][4] = {};
  float amask[4][4] = {};

  f16x8 aq0n = *(const f16x8*)&Q[qbase + quad * 8];
  f16x8 aq1n = *(const f16x8*)&Q[qbase + 32 + quad * 8];
  float4 iln = *(const float4*)&invDen[dbase];

#pragma unroll 1
  for (int h = 0; h < NH; ++h) {
    const f16x8 aq0 = aq0n, aq1 = aq1n;
    const float4 il4 = iln;
    if (h + 1 < NH) { // prefetch next head's Q frags + invDen
      aq0n = *(const f16x8*)&Q[qbase + (size_t)(h + 1) * hstep + quad * 8];
      aq1n = *(const f16x8*)&Q[qbase + (size_t)(h + 1) * hstep + 32 + quad * 8];
      iln = *(const float4*)&invDen[dbase + (size_t)(h + 1) * SDIM];
    }
    const _Float16* Kp = K + (size_t)(b * NH + h) * hstep + (size_t)k0 * DK;
    const float il[4] = {il4.x, il4.y, il4.z, il4.w};
    int anyh = 0;
#pragma unroll
    for (int c = 0; c < 4; ++c) {
      const f16x8 b0 = *(const f16x8*)&Kp[(c * 16 + lr) * DK + quad * 8];
      const f16x8 b1 = *(const f16x8*)&Kp[(c * 16 + lr) * DK + 32 + quad * 8];
      f32x4 acc = {0.f, 0.f, 0.f, 0.f};
      acc = __builtin_amdgcn_mfma_f32_16x16x32_f16(aq0, b0, acc, 0, 0, 0);
      acc = __builtin_amdgcn_mfma_f32_16x16x32_f16(aq1, b1, acc, 0, 0, 0);
#pragma unroll
      for (int r = 0; r < 4; ++r) {
        const float p = __builtin_amdgcn_exp2f(acc[r] * EXPC) * il[r];
        asum[c][r] += p;
        const int hit = p >= 0.1f;
        amask[c][r] += (float)hit;
        anyh |= hit;
      }
    }
    if (__any(anyh)) { // cold path: recompute this head's tile, push events
#pragma unroll 1
      for (int c = 0; c < 4; ++c) {
        const f16x8 b0 = *(const f16x8*)&Kp[(c * 16 + lr) * DK + quad * 8];
        const f16x8 b1 = *(const f16x8*)&Kp[(c * 16 + lr) * DK + 32 + quad * 8];
        f32x4 acc = {0.f, 0.f, 0.f, 0.f};
        acc = __builtin_amdgcn_mfma_f32_16x16x32_f16(aq0, b0, acc, 0, 0, 0);
        acc = __builtin_amdgcn_mfma_f32_16x16x32_f16(aq1, b1, acc, 0, 0, 0);
#pragma unroll 1
        for (int r = 0; r < 4; ++r) {
          const float p = __builtin_amdgcn_exp2f(acc[r] * EXPC) * il[r];
          if (p >= 0.1f) {
            int idx = atomicAdd(ecnt, 1);
            if (idx < MAXEV)
              ev[idx] = make_float4(
                  __int_as_float(b * NH + h),
                  __int_as_float(q0 + wave * 16 + quad * 4 + r),
                  __int_as_float(k0 + c * 16 + lr), p);
          }
        }
      }
    }
  }
  // epilogue: LDS transpose -> full-line float4 stores
  const int orow = t >> 2, ocol = (t & 3) * 16;
  __syncthreads();
#pragma unroll
  for (int c = 0; c < 4; ++c)
#pragma unroll
    for (int r = 0; r < 4; ++r)
      Tbuf[(wave * 16 + quad * 4 + r) * 68 + c * 16 + lr] = asum[c][r];
  __syncthreads();
#pragma unroll
  for (int j = 0; j < 4; ++j) {
    float4 v = *(float4*)&Tbuf[orow * 68 + ocol + j * 4];
    *(float4*)&attSum[((size_t)(b * SDIM) + q0 + orow) * SDIM + k0 + ocol +
                      j * 4] = v;
  }
  __syncthreads();
#pragma unroll
  for (int c = 0; c < 4; ++c)
#pragma unroll
    for (int r = 0; r < 4; ++r)
      Tbuf[(wave * 16 + quad * 4 + r) * 68 + c * 16 + lr] = amask[c][r];
  __syncthreads();
#pragma unroll
  for (int j = 0; j < 4; ++j) {
    float4 v = *(float4*)&Tbuf[orow * 68 + ocol + j * 4];
    *(float4*)&attMask[((size_t)(b * SDIM) + q0 + orow) * SDIM + k0 + ocol +
                       j * 4] = v;
  }
}

// ---------- K3b: apply rare events to merged ctx ----------
__global__ __launch_bounds__(64) void apply_events(
    const float4* __restrict__ ev, const int* __restrict__ ecnt,
    const float* __restrict__ V, float* __restrict__ merged,
    int* __restrict__ flags) {
  int n = *ecnt;
  if (n > MAXEV) n = MAXEV;
  const int d = threadIdx.x;
  for (int e = blockIdx.x; e < n; e += gridDim.x) {
    float4 r = ev[e];
    int bh = __float_as_int(r.x);
    int q = __float_as_int(r.y);
    int kc = __float_as_int(r.z);
    float p = r.w;
    int b = bh >> 4, h = bh & 15;
    atomicAdd(&merged[((size_t)(b * SDIM + q)) * DDIM + h * DK + d],
              p * V[((size_t)bh * SDIM + kc) * DK + d]);
    if (d == 0) flags[b * SDIM + q] = 1;
  }
}

// ---------- K4: output projection with all-zero-row-tile skip ----------
__global__ __launch_bounds__(256) void out_gemm(const float* __restrict__ A,
                                                const float* __restrict__ W,
                                                const float* __restrict__ bias,
                                                float* __restrict__ out,
                                                const int* __restrict__ flags) {
  __shared__ float As[16][68];
  __shared__ float Ws[16][68];
  __shared__ int anyF;
  const int t = threadIdx.x;
  const int tx = t & 15, ty = t >> 4;
  const int m0 = blockIdx.y * 64;
  const int n0 = blockIdx.x * 64;
  if (t == 0) anyF = 0;
  __syncthreads();
  if (t < 64 && flags[m0 + t]) anyF = 1;
  __syncthreads();
  const int nb = n0 + tx * 4;
  const float4 bv = *(const float4*)&bias[nb];
  if (!anyF) {
#pragma unroll
    for (int r = 0; r < 4; ++r)
      *(float4*)&out[(size_t)(m0 + ty * 4 + r) * DDIM + nb] = bv;
    return;
  }
  const int lr = t >> 2;
  const int lc = (t & 3) * 4;
  float acc[4][4] = {};
  for (int k0 = 0; k0 < DDIM; k0 += 16) {
    __syncthreads();
    float4 av = *(const float4*)&A[(size_t)(m0 + lr) * DDIM + k0 + lc];
    float4 wv = *(const float4*)&W[(size_t)(n0 + lr) * DDIM + k0 + lc];
    As[lc + 0][lr] = av.x; As[lc + 1][lr] = av.y;
    As[lc + 2][lr] = av.z; As[lc + 3][lr] = av.w;
    Ws[lc + 0][lr] = wv.x; Ws[lc + 1][lr] = wv.y;
    Ws[lc + 2][lr] = wv.z; Ws[lc + 3][lr] = wv.w;
    __syncthreads();
#pragma unroll
    for (int kk = 0; kk < 16; ++kk) {
      float4 a4 = *(const float4*)&As[kk][ty * 4];
      float4 b4 = *(const float4*)&Ws[kk][tx * 4];
      const float a[4] = {a4.x, a4.y, a4.z, a4.w};
      const float b[4] = {b4.x, b4.y, b4.z, b4.w};
#pragma unroll
      for (int r = 0; r < 4; ++r)
#pragma unroll
        for (int c = 0; c < 4; ++c)
          acc[r][c] = fmaf(a[r], b[c], acc[r][c]);
    }
  }
#pragma unroll
  for (int r = 0; r < 4; ++r) {
    float4 o;
    o.x = acc[r][0] + bv.x;
    o.y = acc[r][1] + bv.y;
    o.z = acc[r][2] + bv.z;
    o.w = acc[r][3] + bv.w;
    *(float4*)&out[(size_t)(m0 + ty * 4 + r) * DDIM + nb] = o;
  }
}

// ---------- launcher ----------
extern "C" void kernel_launch(void* const* d_in, const int* in_sizes, int n_in,
                              void* d_out, int out_size, void* d_ws,
                              size_t ws_size, hipStream_t stream) {
  const float* x = (const float*)d_in[0];
  const float* Wq = (const float*)d_in[1];
  const float* bq = (const float*)d_in[2];
  const float* Wk = (const float*)d_in[3];
  const float* bk = (const float*)d_in[4];
  const float* Wv = (const float*)d_in[5];
  const float* bv = (const float*)d_in[6];
  const float* Wo = (const float*)d_in[7];
  const float* bo = (const float*)d_in[8];

  float* out = (float*)d_out;
  float* attSum = out + (size_t)MROWS * DDIM;
  float* attMask = attSum + (size_t)NB * SDIM * SDIM;

  char* ws = (char*)d_ws;
  const size_t bigF = (size_t)MROWS * DDIM * sizeof(float);    // 16.78 MB
  const size_t bigH = (size_t)MROWS * DDIM * sizeof(_Float16); // 8.39 MB
  const size_t wH = (size_t)DDIM * DDIM * sizeof(_Float16);    // 2.10 MB
  _Float16* Qh = (_Float16*)ws;  ws += bigH;
  _Float16* Kh = (_Float16*)ws;  ws += bigH;
  float* V = (float*)ws;         ws += bigF;
  float* merged = (float*)ws;    ws += bigF;
  _Float16* xh = (_Float16*)ws;  ws += bigH;
  _Float16* Wqh = (_Float16*)ws; ws += wH;
  _Float16* Wkh = (_Float16*)ws; ws += wH;
  _Float16* Wvh = (_Float16*)ws; ws += wH;
  float* invDen = (float*)ws;    ws += (size_t)NB * NH * SDIM * sizeof(float);
  float4* ev = (float4*)ws;      ws += (size_t)MAXEV * sizeof(float4);
  int* flags = (int*)ws;         ws += (size_t)MROWS * sizeof(int);
  int* ecnt = (int*)ws;          ws += 16;

  hipMemsetAsync(merged, 0, bigF, stream);
  hipMemsetAsync(flags, 0, (size_t)MROWS * sizeof(int), stream);
  hipMemsetAsync(ecnt, 0, 16, stream);

  dim3 blk(256);
  cvt_f16<<<dim3(7168), blk, 0, stream>>>(x, Wq, Wk, Wv, xh, Wqh, Wkh, Wvh);
  proj_gemm<<<dim3(8, 32, 3), blk, 0, stream>>>(xh, Wqh, Wkh, Wvh, bq, bk, bv,
                                                Qh, Kh, V);
  attn_denom<<<dim3(32, 32), blk, 0, stream>>>(Qh, Kh, invDen);
  attn_pass2<<<dim3(32, 32, 2), blk, 0, stream>>>(Qh, Kh, invDen, attSum,
                                                  attMask, ev, ecnt);
  apply_events<<<dim3(256), dim3(64), 0, stream>>>(ev, ecnt, V, merged, flags);
  out_gemm<<<dim3(16, 64), blk, 0, stream>>>(merged, Wo, bo, out, flags);
}

// Round 7
// 434.538 us; speedup vs baseline: 1.0011x; 1.0011x over previous
//
#include <hip/hip_runtime.h>

#define SDIM 2048
#define DDIM 1024
#define NH 16
#define DK 64
#define NB 2
#define MROWS (NB * SDIM) // 4096
#define MAXEV 65536
#define EXPC 0.18033688011112f // 0.125 * log2(e)

typedef _Float16 f16x8 __attribute__((ext_vector_type(8)));
typedef _Float16 f16x4 __attribute__((ext_vector_type(4)));
typedef float f32x4 __attribute__((ext_vector_type(4)));

__device__ __forceinline__ void ld_lds16(const _Float16* g, _Float16* l) {
  __builtin_amdgcn_global_load_lds(
      (const __attribute__((address_space(1))) void*)g,
      (__attribute__((address_space(3))) void*)l, 16, 0, 0);
}

// ---------- K0: fp32 -> fp16 convert, all four arrays in one launch ----------
__global__ __launch_bounds__(256) void cvt_f16(
    const float* __restrict__ x, const float* __restrict__ wq,
    const float* __restrict__ wk, const float* __restrict__ wv,
    _Float16* __restrict__ xh, _Float16* __restrict__ wqh,
    _Float16* __restrict__ wkh, _Float16* __restrict__ wvh) {
  int i = blockIdx.x * 256 + threadIdx.x; // float4 index
  const float* src;
  _Float16* dst;
  int off;
  if (i < 1048576) {
    src = x; dst = xh; off = i;
  } else if (i < 1310720) {
    src = wq; dst = wqh; off = i - 1048576;
  } else if (i < 1572864) {
    src = wk; dst = wkh; off = i - 1310720;
  } else {
    src = wv; dst = wvh; off = i - 1572864;
  }
  float4 v = ((const float4*)src)[off];
  f16x4 h;
  h[0] = (_Float16)v.x; h[1] = (_Float16)v.y;
  h[2] = (_Float16)v.z; h[3] = (_Float16)v.w;
  ((f16x4*)dst)[off] = h;
}

// ---------- K1: fused QKV projection, plain fp16 MFMA, 128x128 tile, BK=64 ----------
__global__ __launch_bounds__(256, 2) void proj_gemm(
    const _Float16* __restrict__ xh, const _Float16* __restrict__ Wqh,
    const _Float16* __restrict__ Wkh, const _Float16* __restrict__ Wvh,
    const float* __restrict__ bq, const float* __restrict__ bk,
    const float* __restrict__ bv, _Float16* __restrict__ Qo,
    _Float16* __restrict__ Ko, float* __restrict__ Vo) {
  __shared__ _Float16 sA[128 * 64]; // 16KB, XOR-swizzled chunks
  __shared__ _Float16 sB[128 * 64];
  const int t = threadIdx.x;
  const int lane = t & 63, wv = t >> 6;
  const int lr = lane & 15, quad = lane >> 4;
  const int wm = wv >> 1, wn = wv & 1;
  const int m0 = blockIdx.y * 128, n0 = blockIdx.x * 128;
  const int z = blockIdx.z;
  const _Float16* Bp = z == 0 ? Wqh : (z == 1 ? Wkh : Wvh);
  const float* bias = z == 0 ? bq : (z == 1 ? bk : bv);

  const int strow = t >> 3;            // 0..31 per issue
  const int stchunk = t & 7;           // phys chunk
  const int stsrc = (stchunk ^ (strow & 7)) * 8; // src col (halfs)

  f32x4 acc[4][4];
#pragma unroll
  for (int i = 0; i < 4; ++i)
#pragma unroll
    for (int j = 0; j < 4; ++j) acc[i][j] = (f32x4){0.f, 0.f, 0.f, 0.f};

  for (int k0 = 0; k0 < DDIM; k0 += 64) {
    __syncthreads(); // prior LDS reads complete
#pragma unroll
    for (int i = 0; i < 4; ++i) {
      const int row = i * 32 + strow;
      ld_lds16(&xh[(size_t)(m0 + row) * DDIM + k0 + stsrc],
               &sA[row * 64 + stchunk * 8]);
      ld_lds16(&Bp[(size_t)(n0 + row) * DDIM + k0 + stsrc],
               &sB[row * 64 + stchunk * 8]);
    }
    __syncthreads(); // drains vmcnt: LDS visible
    f16x8 af[4][2], bf[4][2];
#pragma unroll
    for (int i = 0; i < 4; ++i)
#pragma unroll
      for (int kk = 0; kk < 2; ++kk) {
        const int ph = ((kk * 4 + quad) ^ (lr & 7)) * 8;
        af[i][kk] = *(const f16x8*)&sA[(wm * 64 + i * 16 + lr) * 64 + ph];
        bf[i][kk] = *(const f16x8*)&sB[(wn * 64 + i * 16 + lr) * 64 + ph];
      }
#pragma unroll
    for (int kk = 0; kk < 2; ++kk)
#pragma unroll
      for (int i = 0; i < 4; ++i)
#pragma unroll
        for (int j = 0; j < 4; ++j)
          acc[i][j] = __builtin_amdgcn_mfma_f32_16x16x32_f16(
              af[i][kk], bf[j][kk], acc[i][j], 0, 0, 0);
  }
  // epilogue: bias + head-split store (C layout: col=lane&15, row=quad*4+r)
#pragma unroll
  for (int j = 0; j < 4; ++j) {
    const int ng = n0 + wn * 64 + j * 16 + lr;
    const float bvv = bias[ng];
    const int h = ng >> 6, d = ng & 63;
#pragma unroll
    for (int i = 0; i < 4; ++i) {
#pragma unroll
      for (int r = 0; r < 4; ++r) {
        const int mg = m0 + wm * 64 + i * 16 + quad * 4 + r;
        const int b = mg >> 11, s = mg & 2047;
        const float o = acc[i][j][r] + bvv;
        const size_t off = ((size_t)(b * NH + h) * SDIM + s) * DK + d;
        if (z == 0)
          Qo[off] = (_Float16)o;
        else if (z == 1)
          Ko[off] = (_Float16)o;
        else
          Vo[off] = o;
      }
    }
  }
}

// ---------- K2: row denominators. LDS-free, barrier-free; next k-tile's
// K-fragments prefetched into registers one iteration ahead. ----------
__global__ __launch_bounds__(256) void attn_denom(const _Float16* __restrict__ Q,
                                                  const _Float16* __restrict__ K,
                                                  float* __restrict__ invDen) {
  const int t = threadIdx.x;
  const int lane = t & 63, wave = t >> 6;
  const int quad = lane >> 4, lr = lane & 15;
  const int bh = blockIdx.x;
  const int q0 = blockIdx.y * 64;
  const _Float16* Qh = Q + (size_t)bh * SDIM * DK;
  const _Float16* Kh = K + (size_t)bh * SDIM * DK;
  const size_t qoff = (size_t)(q0 + wave * 16 + lr) * DK + quad * 8;
  const f16x8 aq0 = *(const f16x8*)&Qh[qoff];
  const f16x8 aq1 = *(const f16x8*)&Qh[qoff + 32];

  float dsum[4] = {0.f, 0.f, 0.f, 0.f};
  f16x8 kb0[4], kb1[4], kn0[4], kn1[4];
  // load k-tile 0 fragments
#pragma unroll
  for (int c = 0; c < 4; ++c) {
    const size_t ro = (size_t)(c * 16 + lr) * DK + quad * 8;
    kb0[c] = *(const f16x8*)&Kh[ro];
    kb1[c] = *(const f16x8*)&Kh[ro + 32];
  }
#pragma unroll 1
  for (int kt = 0; kt < 32; ++kt) {
    if (kt + 1 < 32) { // prefetch next tile's fragments
      const _Float16* Kn = Kh + (size_t)(kt + 1) * 64 * DK;
#pragma unroll
      for (int c = 0; c < 4; ++c) {
        const size_t ro = (size_t)(c * 16 + lr) * DK + quad * 8;
        kn0[c] = *(const f16x8*)&Kn[ro];
        kn1[c] = *(const f16x8*)&Kn[ro + 32];
      }
    }
#pragma unroll
    for (int c = 0; c < 4; ++c) {
      f32x4 acc = {0.f, 0.f, 0.f, 0.f};
      acc = __builtin_amdgcn_mfma_f32_16x16x32_f16(aq0, kb0[c], acc, 0, 0, 0);
      acc = __builtin_amdgcn_mfma_f32_16x16x32_f16(aq1, kb1[c], acc, 0, 0, 0);
#pragma unroll
      for (int r = 0; r < 4; ++r)
        dsum[r] += __builtin_amdgcn_exp2f(acc[r] * EXPC);
    }
    if (kt + 1 < 32) {
#pragma unroll
      for (int c = 0; c < 4; ++c) { kb0[c] = kn0[c]; kb1[c] = kn1[c]; }
    }
  }
#pragma unroll
  for (int m = 1; m < 16; m <<= 1)
#pragma unroll
    for (int r = 0; r < 4; ++r)
      dsum[r] += __shfl_xor(dsum[r], m, 64);
  if (lr == 0) {
#pragma unroll
    for (int r = 0; r < 4; ++r)
      invDen[(size_t)bh * SDIM + q0 + wave * 16 + quad * 4 + r] =
          1.0f / dsum[r];
  }
}

// ---------- K3: probs -> att_sum/att_mask. LDS-free, barrier-free hot loop;
// next head's K/Q fragments + invDen prefetched into registers one head
// ahead. One __any branch per head; cold path recomputes from registers.
// LDS used only for the store-transpose epilogue. ----------
__global__ __launch_bounds__(256) void attn_pass2(
    const _Float16* __restrict__ Q, const _Float16* __restrict__ K,
    const float* __restrict__ invDen, float* __restrict__ attSum,
    float* __restrict__ attMask, float4* __restrict__ ev,
    int* __restrict__ ecnt) {
  __shared__ float Tbuf[64 * 68]; // epilogue transpose only
  const int t = threadIdx.x;
  const int lane = t & 63, wave = t >> 6;
  const int quad = lane >> 4, lr = lane & 15;
  const int k0 = blockIdx.x * 64;
  const int q0 = blockIdx.y * 64;
  const int b = blockIdx.z;

  const size_t qbase = ((size_t)(b * NH) * SDIM + q0 + wave * 16 + lr) * DK;
  const size_t dbase = (size_t)(b * NH) * SDIM + q0 + wave * 16 + quad * 4;
  const size_t hstep = (size_t)SDIM * DK;

  float asum[4][4] = {};
  float amask[4][4] = {};

  // h=0 fragments
  f16x8 kb0[4], kb1[4], kn0[4], kn1[4];
  {
    const _Float16* Kp = K + (size_t)(b * NH) * hstep + (size_t)k0 * DK;
#pragma unroll
    for (int c = 0; c < 4; ++c) {
      const size_t ro = (size_t)(c * 16 + lr) * DK + quad * 8;
      kb0[c] = *(const f16x8*)&Kp[ro];
      kb1[c] = *(const f16x8*)&Kp[ro + 32];
    }
  }
  f16x8 aq0 = *(const f16x8*)&Q[qbase + quad * 8];
  f16x8 aq1 = *(const f16x8*)&Q[qbase + 32 + quad * 8];
  float4 il4 = *(const float4*)&invDen[dbase];
  f16x8 aq0n, aq1n;
  float4 iln;

#pragma unroll 1
  for (int h = 0; h < NH; ++h) {
    if (h + 1 < NH) { // prefetch next head
      const _Float16* Kn =
          K + (size_t)(b * NH + h + 1) * hstep + (size_t)k0 * DK;
#pragma unroll
      for (int c = 0; c < 4; ++c) {
        const size_t ro = (size_t)(c * 16 + lr) * DK + quad * 8;
        kn0[c] = *(const f16x8*)&Kn[ro];
        kn1[c] = *(const f16x8*)&Kn[ro + 32];
      }
      aq0n = *(const f16x8*)&Q[qbase + (size_t)(h + 1) * hstep + quad * 8];
      aq1n = *(const f16x8*)&Q[qbase + (size_t)(h + 1) * hstep + 32 + quad * 8];
      iln = *(const float4*)&invDen[dbase + (size_t)(h + 1) * SDIM];
    }
    const float il[4] = {il4.x, il4.y, il4.z, il4.w};
    int anyh = 0;
#pragma unroll
    for (int c = 0; c < 4; ++c) {
      f32x4 acc = {0.f, 0.f, 0.f, 0.f};
      acc = __builtin_amdgcn_mfma_f32_16x16x32_f16(aq0, kb0[c], acc, 0, 0, 0);
      acc = __builtin_amdgcn_mfma_f32_16x16x32_f16(aq1, kb1[c], acc, 0, 0, 0);
#pragma unroll
      for (int r = 0; r < 4; ++r) {
        const float p = __builtin_amdgcn_exp2f(acc[r] * EXPC) * il[r];
        asum[c][r] += p;
        const int hit = p >= 0.1f;
        amask[c][r] += (float)hit;
        anyh |= hit;
      }
    }
    if (__any(anyh)) { // cold path: recompute from registers, push events
#pragma unroll 1
      for (int c = 0; c < 4; ++c) {
        f32x4 acc = {0.f, 0.f, 0.f, 0.f};
        acc = __builtin_amdgcn_mfma_f32_16x16x32_f16(aq0, kb0[c], acc, 0, 0, 0);
        acc = __builtin_amdgcn_mfma_f32_16x16x32_f16(aq1, kb1[c], acc, 0, 0, 0);
#pragma unroll 1
        for (int r = 0; r < 4; ++r) {
          const float p = __builtin_amdgcn_exp2f(acc[r] * EXPC) * il[r];
          if (p >= 0.1f) {
            int idx = atomicAdd(ecnt, 1);
            if (idx < MAXEV)
              ev[idx] = make_float4(
                  __int_as_float(b * NH + h),
                  __int_as_float(q0 + wave * 16 + quad * 4 + r),
                  __int_as_float(k0 + c * 16 + lr), p);
          }
        }
      }
    }
    if (h + 1 < NH) { // rotate buffers
#pragma unroll
      for (int c = 0; c < 4; ++c) { kb0[c] = kn0[c]; kb1[c] = kn1[c]; }
      aq0 = aq0n; aq1 = aq1n; il4 = iln;
    }
  }
  // epilogue: LDS transpose -> full-line float4 stores
  const int orow = t >> 2, ocol = (t & 3) * 16;
  __syncthreads();
#pragma unroll
  for (int c = 0; c < 4; ++c)
#pragma unroll
    for (int r = 0; r < 4; ++r)
      Tbuf[(wave * 16 + quad * 4 + r) * 68 + c * 16 + lr] = asum[c][r];
  __syncthreads();
#pragma unroll
  for (int j = 0; j < 4; ++j) {
    float4 v = *(float4*)&Tbuf[orow * 68 + ocol + j * 4];
    *(float4*)&attSum[((size_t)(b * SDIM) + q0 + orow) * SDIM + k0 + ocol +
                      j * 4] = v;
  }
  __syncthreads();
#pragma unroll
  for (int c = 0; c < 4; ++c)
#pragma unroll
    for (int r = 0; r < 4; ++r)
      Tbuf[(wave * 16 + quad * 4 + r) * 68 + c * 16 + lr] = amask[c][r];
  __syncthreads();
#pragma unroll
  for (int j = 0; j < 4; ++j) {
    float4 v = *(float4*)&Tbuf[orow * 68 + ocol + j * 4];
    *(float4*)&attMask[((size_t)(b * SDIM) + q0 + orow) * SDIM + k0 + ocol +
                       j * 4] = v;
  }
}

// ---------- K3b: apply rare events to merged ctx ----------
__global__ __launch_bounds__(64) void apply_events(
    const float4* __restrict__ ev, const int* __restrict__ ecnt,
    const float* __restrict__ V, float* __restrict__ merged,
    int* __restrict__ flags) {
  int n = *ecnt;
  if (n > MAXEV) n = MAXEV;
  const int d = threadIdx.x;
  for (int e = blockIdx.x; e < n; e += gridDim.x) {
    float4 r = ev[e];
    int bh = __float_as_int(r.x);
    int q = __float_as_int(r.y);
    int kc = __float_as_int(r.z);
    float p = r.w;
    int b = bh >> 4, h = bh & 15;
    atomicAdd(&merged[((size_t)(b * SDIM + q)) * DDIM + h * DK + d],
              p * V[((size_t)bh * SDIM + kc) * DK + d]);
    if (d == 0) flags[b * SDIM + q] = 1;
  }
}

// ---------- K4: output projection with all-zero-row-tile skip ----------
__global__ __launch_bounds__(256) void out_gemm(const float* __restrict__ A,
                                                const float* __restrict__ W,
                                                const float* __restrict__ bias,
                                                float* __restrict__ out,
                                                const int* __restrict__ flags) {
  __shared__ float As[16][68];
  __shared__ float Ws[16][68];
  __shared__ int anyF;
  const int t = threadIdx.x;
  const int tx = t & 15, ty = t >> 4;
  const int m0 = blockIdx.y * 64;
  const int n0 = blockIdx.x * 64;
  if (t == 0) anyF = 0;
  __syncthreads();
  if (t < 64 && flags[m0 + t]) anyF = 1;
  __syncthreads();
  const int nb = n0 + tx * 4;
  const float4 bv = *(const float4*)&bias[nb];
  if (!anyF) {
#pragma unroll
    for (int r = 0; r < 4; ++r)
      *(float4*)&out[(size_t)(m0 + ty * 4 + r) * DDIM + nb] = bv;
    return;
  }
  const int lr = t >> 2;
  const int lc = (t & 3) * 4;
  float acc[4][4] = {};
  for (int k0 = 0; k0 < DDIM; k0 += 16) {
    __syncthreads();
    float4 av = *(const float4*)&A[(size_t)(m0 + lr) * DDIM + k0 + lc];
    float4 wv = *(const float4*)&W[(size_t)(n0 + lr) * DDIM + k0 + lc];
    As[lc + 0][lr] = av.x; As[lc + 1][lr] = av.y;
    As[lc + 2][lr] = av.z; As[lc + 3][lr] = av.w;
    Ws[lc + 0][lr] = wv.x; Ws[lc + 1][lr] = wv.y;
    Ws[lc + 2][lr] = wv.z; Ws[lc + 3][lr] = wv.w;
    __syncthreads();
#pragma unroll
    for (int kk = 0; kk < 16; ++kk) {
      float4 a4 = *(const float4*)&As[kk][ty * 4];
      float4 b4 = *(const float4*)&Ws[kk][tx * 4];
      const float a[4] = {a4.x, a4.y, a4.z, a4.w};
      const float b[4] = {b4.x, b4.y, b4.z, b4.w};
#pragma unroll
      for (int r = 0; r < 4; ++r)
#pragma unroll
        for (int c = 0; c < 4; ++c)
          acc[r][c] = fmaf(a[r], b[c], acc[r][c]);
    }
  }
#pragma unroll
  for (int r = 0; r < 4; ++r) {
    float4 o;
    o.x = acc[r][0] + bv.x;
    o.y = acc[r][1] + bv.y;
    o.z = acc[r][2] + bv.z;
    o.w = acc[r][3] + bv.w;
    *(float4*)&out[(size_t)(m0 + ty * 4 + r) * DDIM + nb] = o;
  }
}

// ---------- launcher ----------
extern "C" void kernel_launch(void* const* d_in, const int* in_sizes, int n_in,
                              void* d_out, int out_size, void* d_ws,
                              size_t ws_size, hipStream_t stream) {
  const float* x = (const float*)d_in[0];
  const float* Wq = (const float*)d_in[1];
  const float* bq = (const float*)d_in[2];
  const float* Wk = (const float*)d_in[3];
  const float* bk = (const float*)d_in[4];
  const float* Wv = (const float*)d_in[5];
  const float* bv = (const float*)d_in[6];
  const float* Wo = (const float*)d_in[7];
  const float* bo = (const float*)d_in[8];

  float* out = (float*)d_out;
  float* attSum = out + (size_t)MROWS * DDIM;
  float* attMask = attSum + (size_t)NB * SDIM * SDIM;

  char* ws = (char*)d_ws;
  const size_t bigF = (size_t)MROWS * DDIM * sizeof(float);    // 16.78 MB
  const size_t bigH = (size_t)MROWS * DDIM * sizeof(_Float16); // 8.39 MB
  const size_t wH = (size_t)DDIM * DDIM * sizeof(_Float16);    // 2.10 MB
  _Float16* Qh = (_Float16*)ws;  ws += bigH;
  _Float16* Kh = (_Float16*)ws;  ws += bigH;
  float* V = (float*)ws;         ws += bigF;
  float* merged = (float*)ws;    ws += bigF;
  _Float16* xh = (_Float16*)ws;  ws += bigH;
  _Float16* Wqh = (_Float16*)ws; ws += wH;
  _Float16* Wkh = (_Float16*)ws; ws += wH;
  _Float16* Wvh = (_Float16*)ws; ws += wH;
  float* invDen = (float*)ws;    ws += (size_t)NB * NH * SDIM * sizeof(float);
  float4* ev = (float4*)ws;      ws += (size_t)MAXEV * sizeof(float4);
  int* flags = (int*)ws;         ws += (size_t)MROWS * sizeof(int);
  int* ecnt = (int*)ws;          ws += 16;

  hipMemsetAsync(merged, 0, bigF, stream);
  hipMemsetAsync(flags, 0, (size_t)MROWS * sizeof(int), stream);
  hipMemsetAsync(ecnt, 0, 16, stream);

  dim3 blk(256);
  cvt_f16<<<dim3(7168), blk, 0, stream>>>(x, Wq, Wk, Wv, xh, Wqh, Wkh, Wvh);
  proj_gemm<<<dim3(8, 32, 3), blk, 0, stream>>>(xh, Wqh, Wkh, Wvh, bq, bk, bv,
                                                Qh, Kh, V);
  attn_denom<<<dim3(32, 32), blk, 0, stream>>>(Qh, Kh, invDen);
  attn_pass2<<<dim3(32, 32, 2), blk, 0, stream>>>(Qh, Kh, invDen, attSum,
                                                  attMask, ev, ecnt);
  apply_events<<<dim3(256), dim3(64), 0, stream>>>(ev, ecnt, V, merged, flags);
  out_gemm<<<dim3(16, 64), blk, 0, stream>>>(merged, Wo, bo, out, flags);
}

// Round 8
// 250.702 us; speedup vs baseline: 1.7353x; 1.7333x over previous
//
#include <hip/hip_runtime.h>

#define SDIM 2048
#define DDIM 1024
#define NH 16
#define DK 64
#define NB 2
#define MROWS (NB * SDIM) // 4096
#define MAXEV 65536
#define EXPC 0.18033688011112f // 0.125 * log2(e), folded into Q at projection
#define L01 -3.3219281f        // log2(0.1)

typedef _Float16 f16x8 __attribute__((ext_vector_type(8)));
typedef _Float16 f16x4 __attribute__((ext_vector_type(4)));
typedef float f32x4 __attribute__((ext_vector_type(4)));

__device__ __forceinline__ void ld_lds16(const _Float16* g, _Float16* l) {
  __builtin_amdgcn_global_load_lds(
      (const __attribute__((address_space(1))) void*)g,
      (__attribute__((address_space(3))) void*)l, 16, 0, 0);
}

// ---------- K0: fp32 -> fp16 convert, all four arrays in one launch ----------
__global__ __launch_bounds__(256) void cvt_f16(
    const float* __restrict__ x, const float* __restrict__ wq,
    const float* __restrict__ wk, const float* __restrict__ wv,
    _Float16* __restrict__ xh, _Float16* __restrict__ wqh,
    _Float16* __restrict__ wkh, _Float16* __restrict__ wvh) {
  int i = blockIdx.x * 256 + threadIdx.x; // float4 index
  const float* src;
  _Float16* dst;
  int off;
  if (i < 1048576) {
    src = x; dst = xh; off = i;
  } else if (i < 1310720) {
    src = wq; dst = wqh; off = i - 1048576;
  } else if (i < 1572864) {
    src = wk; dst = wkh; off = i - 1310720;
  } else {
    src = wv; dst = wvh; off = i - 1572864;
  }
  float4 v = ((const float4*)src)[off];
  f16x4 h;
  h[0] = (_Float16)v.x; h[1] = (_Float16)v.y;
  h[2] = (_Float16)v.z; h[3] = (_Float16)v.w;
  ((f16x4*)dst)[off] = h;
}

// ---------- K1: fused QKV projection, fp16 MFMA, 128x128 tile, BK=64.
// Q output is pre-scaled by EXPC so attention scores come out of MFMA as
// exp2 arguments directly. ----------
__global__ __launch_bounds__(256, 2) void proj_gemm(
    const _Float16* __restrict__ xh, const _Float16* __restrict__ Wqh,
    const _Float16* __restrict__ Wkh, const _Float16* __restrict__ Wvh,
    const float* __restrict__ bq, const float* __restrict__ bk,
    const float* __restrict__ bv, _Float16* __restrict__ Qo,
    _Float16* __restrict__ Ko, float* __restrict__ Vo) {
  __shared__ _Float16 sA[128 * 64]; // 16KB, XOR-swizzled chunks
  __shared__ _Float16 sB[128 * 64];
  const int t = threadIdx.x;
  const int lane = t & 63, wv = t >> 6;
  const int lr = lane & 15, quad = lane >> 4;
  const int wm = wv >> 1, wn = wv & 1;
  const int m0 = blockIdx.y * 128, n0 = blockIdx.x * 128;
  const int z = blockIdx.z;
  const _Float16* Bp = z == 0 ? Wqh : (z == 1 ? Wkh : Wvh);
  const float* bias = z == 0 ? bq : (z == 1 ? bk : bv);

  const int strow = t >> 3;            // 0..31 per issue
  const int stchunk = t & 7;           // phys chunk
  const int stsrc = (stchunk ^ (strow & 7)) * 8; // src col (halfs)

  f32x4 acc[4][4];
#pragma unroll
  for (int i = 0; i < 4; ++i)
#pragma unroll
    for (int j = 0; j < 4; ++j) acc[i][j] = (f32x4){0.f, 0.f, 0.f, 0.f};

  for (int k0 = 0; k0 < DDIM; k0 += 64) {
    __syncthreads(); // prior LDS reads complete
#pragma unroll
    for (int i = 0; i < 4; ++i) {
      const int row = i * 32 + strow;
      ld_lds16(&xh[(size_t)(m0 + row) * DDIM + k0 + stsrc],
               &sA[row * 64 + stchunk * 8]);
      ld_lds16(&Bp[(size_t)(n0 + row) * DDIM + k0 + stsrc],
               &sB[row * 64 + stchunk * 8]);
    }
    __syncthreads(); // drains vmcnt: LDS visible
    f16x8 af[4][2], bf[4][2];
#pragma unroll
    for (int i = 0; i < 4; ++i)
#pragma unroll
      for (int kk = 0; kk < 2; ++kk) {
        const int ph = ((kk * 4 + quad) ^ (lr & 7)) * 8;
        af[i][kk] = *(const f16x8*)&sA[(wm * 64 + i * 16 + lr) * 64 + ph];
        bf[i][kk] = *(const f16x8*)&sB[(wn * 64 + i * 16 + lr) * 64 + ph];
      }
#pragma unroll
    for (int kk = 0; kk < 2; ++kk)
#pragma unroll
      for (int i = 0; i < 4; ++i)
#pragma unroll
        for (int j = 0; j < 4; ++j)
          acc[i][j] = __builtin_amdgcn_mfma_f32_16x16x32_f16(
              af[i][kk], bf[j][kk], acc[i][j], 0, 0, 0);
  }
  // epilogue: bias + head-split store (C layout: col=lane&15, row=quad*4+r)
#pragma unroll
  for (int j = 0; j < 4; ++j) {
    const int ng = n0 + wn * 64 + j * 16 + lr;
    const float bvv = bias[ng];
    const int h = ng >> 6, d = ng & 63;
#pragma unroll
    for (int i = 0; i < 4; ++i) {
#pragma unroll
      for (int r = 0; r < 4; ++r) {
        const int mg = m0 + wm * 64 + i * 16 + quad * 4 + r;
        const int b = mg >> 11, s = mg & 2047;
        const float o = acc[i][j][r] + bvv;
        const size_t off = ((size_t)(b * NH + h) * SDIM + s) * DK + d;
        if (z == 0)
          Qo[off] = (_Float16)(o * EXPC); // pre-scaled Q
        else if (z == 1)
          Ko[off] = (_Float16)o;
        else
          Vo[off] = o;
      }
    }
  }
}

// ---------- K2: la = -log2(sum_k 2^(Q'.K)) per row. Two-barrier LDS staging,
// 128 K-rows per stage. ----------
__global__ __launch_bounds__(256) void attn_denom(const _Float16* __restrict__ Q,
                                                  const _Float16* __restrict__ K,
                                                  float* __restrict__ laOut) {
  __shared__ _Float16 Ks[128 * 64]; // 16KB
  const int t = threadIdx.x;
  const int lane = t & 63, wave = t >> 6;
  const int quad = lane >> 4, lr = lane & 15;
  const int q0 = blockIdx.x * 64;
  const int bh = blockIdx.y;
  const _Float16* Qh = Q + (size_t)bh * SDIM * DK;
  const _Float16* Kh = K + (size_t)bh * SDIM * DK;
  const size_t qoff = (size_t)(q0 + wave * 16 + lr) * DK + quad * 8;
  const f16x8 aq0 = *(const f16x8*)&Qh[qoff];
  const f16x8 aq1 = *(const f16x8*)&Qh[qoff + 32];
  const int strow = t >> 3, stchunk = t & 7;
  const int stsrc = (stchunk ^ (strow & 7)) * 8;
  const int ph0 = (quad ^ (lr & 7)) * 8;
  const int ph1 = ((4 + quad) ^ (lr & 7)) * 8;

  float dsum[4] = {0.f, 0.f, 0.f, 0.f};
#pragma unroll 1
  for (int kt = 0; kt < 16; ++kt) {
    __syncthreads(); // prior stage's reads done
#pragma unroll
    for (int i = 0; i < 4; ++i)
      ld_lds16(&Kh[(size_t)(kt * 128 + i * 32 + strow) * DK + stsrc],
               &Ks[(i * 32 + strow) * 64 + stchunk * 8]);
    __syncthreads(); // DMA drained
#pragma unroll
    for (int c = 0; c < 8; ++c) {
      f16x8 b0 = *(const f16x8*)&Ks[(c * 16 + lr) * 64 + ph0];
      f16x8 b1 = *(const f16x8*)&Ks[(c * 16 + lr) * 64 + ph1];
      f32x4 acc = {0.f, 0.f, 0.f, 0.f};
      acc = __builtin_amdgcn_mfma_f32_16x16x32_f16(aq0, b0, acc, 0, 0, 0);
      acc = __builtin_amdgcn_mfma_f32_16x16x32_f16(aq1, b1, acc, 0, 0, 0);
#pragma unroll
      for (int r = 0; r < 4; ++r)
        dsum[r] += __builtin_amdgcn_exp2f(acc[r]);
    }
  }
#pragma unroll
  for (int m = 1; m < 16; m <<= 1)
#pragma unroll
    for (int r = 0; r < 4; ++r)
      dsum[r] += __shfl_xor(dsum[r], m, 64);
  if (lr == 0) {
#pragma unroll
    for (int r = 0; r < 4; ++r)
      laOut[(size_t)bh * SDIM + q0 + wave * 16 + quad * 4 + r] =
          -__builtin_amdgcn_logf(dsum[r]); // -log2(dsum)
  }
}

// ---------- K3: att_sum dense; hot path = add,exp,add,max per prob.
// Two-barrier LDS staging, 2 heads per stage. Mask hits tracked by a single
// running max of the exp2 argument; cold path (never taken) recomputes
// amask + events with direct global loads. ----------
__global__ __launch_bounds__(256) void attn_pass2(
    const _Float16* __restrict__ Q, const _Float16* __restrict__ K,
    const float* __restrict__ la, float* __restrict__ attSum,
    float* __restrict__ attMask, float4* __restrict__ ev,
    int* __restrict__ ecnt) {
  __shared__ float SMEM[64 * 68]; // 17.4KB; first 16KB = 2-head K stage
  _Float16* Khs = (_Float16*)SMEM;
  float* Tbuf = SMEM;
  const int t = threadIdx.x;
  const int lane = t & 63, wave = t >> 6;
  const int quad = lane >> 4, lr = lane & 15;
  const int k0 = blockIdx.x * 64;
  const int q0 = blockIdx.y * 64;
  const int b = blockIdx.z;
  const int strow = t >> 3, stchunk = t & 7;
  const int stsrc = (stchunk ^ (strow & 7)) * 8;
  const int ph0 = (quad ^ (lr & 7)) * 8;
  const int ph1 = ((4 + quad) ^ (lr & 7)) * 8;

  const size_t qbase = ((size_t)(b * NH) * SDIM + q0 + wave * 16 + lr) * DK;
  const size_t dbase = (size_t)(b * NH) * SDIM + q0 + wave * 16 + quad * 4;
  const size_t hstep = (size_t)SDIM * DK;

  float asum[4][4] = {};
  float amask[4][4] = {};
  float mx = -1e30f;

#pragma unroll 1
  for (int hp = 0; hp < 8; ++hp) {
    __syncthreads(); // prior stage's LDS reads done
#pragma unroll
    for (int hh = 0; hh < 2; ++hh) {
      const _Float16* Kp =
          K + (size_t)(b * NH + 2 * hp + hh) * hstep + (size_t)k0 * DK;
#pragma unroll
      for (int i = 0; i < 2; ++i)
        ld_lds16(&Kp[(size_t)(i * 32 + strow) * DK + stsrc],
                 &Khs[hh * 4096 + (i * 32 + strow) * 64 + stchunk * 8]);
    }
    f16x8 a0[2], a1[2];
    float4 lav[2];
#pragma unroll
    for (int hh = 0; hh < 2; ++hh) {
      const size_t ho = (size_t)(2 * hp + hh) * hstep;
      a0[hh] = *(const f16x8*)&Q[qbase + ho + quad * 8];
      a1[hh] = *(const f16x8*)&Q[qbase + ho + 32 + quad * 8];
      lav[hh] = *(const float4*)&la[dbase + (size_t)(2 * hp + hh) * SDIM];
    }
    __syncthreads(); // drains DMA (and the Q/la loads)
#pragma unroll
    for (int hh = 0; hh < 2; ++hh) {
      const _Float16* Ks = &Khs[hh * 4096];
      const float lar[4] = {lav[hh].x, lav[hh].y, lav[hh].z, lav[hh].w};
#pragma unroll
      for (int c = 0; c < 4; ++c) {
        f16x8 b0 = *(const f16x8*)&Ks[(c * 16 + lr) * 64 + ph0];
        f16x8 b1 = *(const f16x8*)&Ks[(c * 16 + lr) * 64 + ph1];
        f32x4 acc = {0.f, 0.f, 0.f, 0.f};
        acc = __builtin_amdgcn_mfma_f32_16x16x32_f16(a0[hh], b0, acc, 0, 0, 0);
        acc = __builtin_amdgcn_mfma_f32_16x16x32_f16(a1[hh], b1, acc, 0, 0, 0);
#pragma unroll
        for (int r = 0; r < 4; ++r) {
          const float arg = acc[r] + lar[r];
          mx = fmaxf(mx, arg);
          asum[c][r] += __builtin_amdgcn_exp2f(arg);
        }
      }
    }
  }
  if (__any(mx >= L01)) { // cold: recompute everything with direct loads
#pragma unroll 1
    for (int h = 0; h < NH; ++h) {
      const _Float16* Kp =
          K + (size_t)(b * NH + h) * hstep + (size_t)k0 * DK;
      const size_t ho = (size_t)h * hstep;
      const f16x8 aq0 = *(const f16x8*)&Q[qbase + ho + quad * 8];
      const f16x8 aq1 = *(const f16x8*)&Q[qbase + ho + 32 + quad * 8];
      const float4 l4 = *(const float4*)&la[dbase + (size_t)h * SDIM];
      const float lar[4] = {l4.x, l4.y, l4.z, l4.w};
#pragma unroll 1
      for (int c = 0; c < 4; ++c) {
        const f16x8 b0 = *(const f16x8*)&Kp[(c * 16 + lr) * DK + quad * 8];
        const f16x8 b1 = *(const f16x8*)&Kp[(c * 16 + lr) * DK + 32 + quad * 8];
        f32x4 acc = {0.f, 0.f, 0.f, 0.f};
        acc = __builtin_amdgcn_mfma_f32_16x16x32_f16(aq0, b0, acc, 0, 0, 0);
        acc = __builtin_amdgcn_mfma_f32_16x16x32_f16(aq1, b1, acc, 0, 0, 0);
#pragma unroll 1
        for (int r = 0; r < 4; ++r) {
          const float p = __builtin_amdgcn_exp2f(acc[r] + lar[r]);
          if (p >= 0.1f) {
            amask[c][r] += 1.0f;
            int idx = atomicAdd(ecnt, 1);
            if (idx < MAXEV)
              ev[idx] = make_float4(
                  __int_as_float(b * NH + h),
                  __int_as_float(q0 + wave * 16 + quad * 4 + r),
                  __int_as_float(k0 + c * 16 + lr), p);
          }
        }
      }
    }
  }
  // epilogue: LDS transpose -> full-line float4 stores
  const int orow = t >> 2, ocol = (t & 3) * 16;
  __syncthreads();
#pragma unroll
  for (int c = 0; c < 4; ++c)
#pragma unroll
    for (int r = 0; r < 4; ++r)
      Tbuf[(wave * 16 + quad * 4 + r) * 68 + c * 16 + lr] = asum[c][r];
  __syncthreads();
#pragma unroll
  for (int j = 0; j < 4; ++j) {
    float4 v = *(float4*)&Tbuf[orow * 68 + ocol + j * 4];
    *(float4*)&attSum[((size_t)(b * SDIM) + q0 + orow) * SDIM + k0 + ocol +
                      j * 4] = v;
  }
  __syncthreads();
#pragma unroll
  for (int c = 0; c < 4; ++c)
#pragma unroll
    for (int r = 0; r < 4; ++r)
      Tbuf[(wave * 16 + quad * 4 + r) * 68 + c * 16 + lr] = amask[c][r];
  __syncthreads();
#pragma unroll
  for (int j = 0; j < 4; ++j) {
    float4 v = *(float4*)&Tbuf[orow * 68 + ocol + j * 4];
    *(float4*)&attMask[((size_t)(b * SDIM) + q0 + orow) * SDIM + k0 + ocol +
                       j * 4] = v;
  }
}

// ---------- K3b: apply rare events to merged ctx ----------
__global__ __launch_bounds__(64) void apply_events(
    const float4* __restrict__ ev, const int* __restrict__ ecnt,
    const float* __restrict__ V, float* __restrict__ merged,
    int* __restrict__ flags) {
  int n = *ecnt;
  if (n > MAXEV) n = MAXEV;
  const int d = threadIdx.x;
  for (int e = blockIdx.x; e < n; e += gridDim.x) {
    float4 r = ev[e];
    int bh = __float_as_int(r.x);
    int q = __float_as_int(r.y);
    int kc = __float_as_int(r.z);
    float p = r.w;
    int b = bh >> 4, h = bh & 15;
    atomicAdd(&merged[((size_t)(b * SDIM + q)) * DDIM + h * DK + d],
              p * V[((size_t)bh * SDIM + kc) * DK + d]);
    if (d == 0) flags[b * SDIM + q] = 1;
  }
}

// ---------- K4: output projection with all-zero-row-tile skip ----------
__global__ __launch_bounds__(256) void out_gemm(const float* __restrict__ A,
                                                const float* __restrict__ W,
                                                const float* __restrict__ bias,
                                                float* __restrict__ out,
                                                const int* __restrict__ flags) {
  __shared__ float As[16][68];
  __shared__ float Ws[16][68];
  __shared__ int anyF;
  const int t = threadIdx.x;
  const int tx = t & 15, ty = t >> 4;
  const int m0 = blockIdx.y * 64;
  const int n0 = blockIdx.x * 64;
  if (t == 0) anyF = 0;
  __syncthreads();
  if (t < 64 && flags[m0 + t]) anyF = 1;
  __syncthreads();
  const int nb = n0 + tx * 4;
  const float4 bv = *(const float4*)&bias[nb];
  if (!anyF) {
#pragma unroll
    for (int r = 0; r < 4; ++r)
      *(float4*)&out[(size_t)(m0 + ty * 4 + r) * DDIM + nb] = bv;
    return;
  }
  const int lr = t >> 2;
  const int lc = (t & 3) * 4;
  float acc[4][4] = {};
  for (int k0 = 0; k0 < DDIM; k0 += 16) {
    __syncthreads();
    float4 av = *(const float4*)&A[(size_t)(m0 + lr) * DDIM + k0 + lc];
    float4 wv = *(const float4*)&W[(size_t)(n0 + lr) * DDIM + k0 + lc];
    As[lc + 0][lr] = av.x; As[lc + 1][lr] = av.y;
    As[lc + 2][lr] = av.z; As[lc + 3][lr] = av.w;
    Ws[lc + 0][lr] = wv.x; Ws[lc + 1][lr] = wv.y;
    Ws[lc + 2][lr] = wv.z; Ws[lc + 3][lr] = wv.w;
    __syncthreads();
#pragma unroll
    for (int kk = 0; kk < 16; ++kk) {
      float4 a4 = *(const float4*)&As[kk][ty * 4];
      float4 b4 = *(const float4*)&Ws[kk][tx * 4];
      const float a[4] = {a4.x, a4.y, a4.z, a4.w};
      const float b[4] = {b4.x, b4.y, b4.z, b4.w};
#pragma unroll
      for (int r = 0; r < 4; ++r)
#pragma unroll
        for (int c = 0; c < 4; ++c)
          acc[r][c] = fmaf(a[r], b[c], acc[r][c]);
    }
  }
#pragma unroll
  for (int r = 0; r < 4; ++r) {
    float4 o;
    o.x = acc[r][0] + bv.x;
    o.y = acc[r][1] + bv.y;
    o.z = acc[r][2] + bv.z;
    o.w = acc[r][3] + bv.w;
    *(float4*)&out[(size_t)(m0 + ty * 4 + r) * DDIM + nb] = o;
  }
}

// ---------- launcher ----------
extern "C" void kernel_launch(void* const* d_in, const int* in_sizes, int n_in,
                              void* d_out, int out_size, void* d_ws,
                              size_t ws_size, hipStream_t stream) {
  const float* x = (const float*)d_in[0];
  const float* Wq = (const float*)d_in[1];
  const float* bq = (const float*)d_in[2];
  const float* Wk = (const float*)d_in[3];
  const float* bk = (const float*)d_in[4];
  const float* Wv = (const float*)d_in[5];
  const float* bv = (const float*)d_in[6];
  const float* Wo = (const float*)d_in[7];
  const float* bo = (const float*)d_in[8];

  float* out = (float*)d_out;
  float* attSum = out + (size_t)MROWS * DDIM;
  float* attMask = attSum + (size_t)NB * SDIM * SDIM;

  char* ws = (char*)d_ws;
  const size_t bigF = (size_t)MROWS * DDIM * sizeof(float);    // 16.78 MB
  const size_t bigH = (size_t)MROWS * DDIM * sizeof(_Float16); // 8.39 MB
  const size_t wH = (size_t)DDIM * DDIM * sizeof(_Float16);    // 2.10 MB
  _Float16* Qh = (_Float16*)ws;  ws += bigH;
  _Float16* Kh = (_Float16*)ws;  ws += bigH;
  float* V = (float*)ws;         ws += bigF;
  float* merged = (float*)ws;    ws += bigF;
  _Float16* xh = (_Float16*)ws;  ws += bigH;
  _Float16* Wqh = (_Float16*)ws; ws += wH;
  _Float16* Wkh = (_Float16*)ws; ws += wH;
  _Float16* Wvh = (_Float16*)ws; ws += wH;
  float* laBuf = (float*)ws;     ws += (size_t)NB * NH * SDIM * sizeof(float);
  float4* ev = (float4*)ws;      ws += (size_t)MAXEV * sizeof(float4);
  int* flags = (int*)ws;         ws += (size_t)MROWS * sizeof(int);
  int* ecnt = (int*)ws;          ws += 16;

  hipMemsetAsync(merged, 0, bigF, stream);
  hipMemsetAsync(flags, 0, (size_t)MROWS * sizeof(int), stream);
  hipMemsetAsync(ecnt, 0, 16, stream);

  dim3 blk(256);
  cvt_f16<<<dim3(7168), blk, 0, stream>>>(x, Wq, Wk, Wv, xh, Wqh, Wkh, Wvh);
  proj_gemm<<<dim3(8, 32, 3), blk, 0, stream>>>(xh, Wqh, Wkh, Wvh, bq, bk, bv,
                                                Qh, Kh, V);
  attn_denom<<<dim3(32, 32), blk, 0, stream>>>(Qh, Kh, laBuf);
  attn_pass2<<<dim3(32, 32, 2), blk, 0, stream>>>(Qh, Kh, laBuf, attSum,
                                                  attMask, ev, ecnt);
  apply_events<<<dim3(256), dim3(64), 0, stream>>>(ev, ecnt, V, merged, flags);
  out_gemm<<<dim3(16, 64), blk, 0, stream>>>(merged, Wo, bo, out, flags);
}